// Round 24
// baseline (535.500 us; speedup 1.0000x reference)
//
#include <hip/hip_runtime.h>
#include <hip/hip_bf16.h>
#include <cstdint>
#include <cstddef>

#define MAX_K 70
#define BN_EPS 1e-5f
#define KPAD 360
#define NPOOL 16
#define ACHUNK 2048
#define BCHUNK 2048
#define CCAP 3584   // max items per 128-comp sub-bucket staged in LDS (~13 sigma)
#define NSBMAX 2048 // LDS histogram bins (>= 8 * nsb)
#define NDCOPY 64   // BN-stat atomic spreading copies
#define DSTRIDE 1408 // floats per copy: (32+64+128+256)*2

typedef __attribute__((ext_vector_type(4))) float f32x4;
typedef __attribute__((ext_vector_type(8))) short bf16x8;
typedef __attribute__((ext_vector_type(4))) int i32x4;

__device__ inline float loadv(const float* p, size_t i) { return p[i]; }
__device__ inline float loadv(const __hip_bfloat16* p, size_t i) {
    return __bfloat162float(p[i]);
}
__device__ inline void storev(float* p, size_t i, float v) { p[i] = v; }
__device__ inline void storev(__hip_bfloat16* p, size_t i, float v) {
    p[i] = __float2bfloat16(v);
}
__device__ inline float bf2f(unsigned short u) {
    union { unsigned int i; float f; } x; x.i = ((unsigned int)u) << 16; return x.f;
}
__device__ inline unsigned short f2bfu(float f) {
    __hip_bfloat16 h = __float2bfloat16(f);
    return *reinterpret_cast<unsigned short*>(&h);
}

// ---- hist1568: LDS-aggregated sub-bucket histogram (+ fused imgcnt) ------
__global__ __launch_bounds__(256) void hist_kernel(
    const i32x4* __restrict__ cc4, int* __restrict__ sbsize,
    const int* __restrict__ imgid, int* __restrict__ pcnt,
    int n4, int C, int cg, int nsb, int B) {
    __shared__ int h[NSBMAX];
    __shared__ int scnt[64];
    int tid = threadIdx.x;
    int nsbtot = 8 * nsb;
    for (int t = tid; t < nsbtot; t += 256) h[t] = 0;
    if (tid < B) scnt[tid] = 0;
    __syncthreads();
    int per = (n4 + gridDim.x - 1) / gridDim.x;
    int q0 = blockIdx.x * per, q1 = min(q0 + per, n4);
    for (int q = q0 + tid; q < q1; q += 256) {
        i32x4 v = cc4[q];
        #pragma unroll
        for (int e = 0; e < 4; ++e) {
            int c = v[e];
            int g = c / cg;
            int loc = c - g * cg;
            atomicAdd(&h[g * nsb + (loc >> 7)], 1);
        }
    }
    for (int i = blockIdx.x * 256 + tid; i < C; i += gridDim.x * 256)
        atomicAdd(&scnt[imgid[i]], 1);
    __syncthreads();
    for (int t = tid; t < nsbtot; t += 256) {
        int v = h[t];
        if (v) atomicAdd(&sbsize[t], v);
    }
    if (tid < B) {
        int v = scnt[tid];
        if (v) atomicAdd(&pcnt[tid], v);
    }
}

// ---- weight prep: w4t[256][128], w1t[32][352], w3t[128][64] --------------
__global__ void prep_kernel(const float* __restrict__ W4,
                            const float* __restrict__ W1,
                            const float* __restrict__ W3,
                            unsigned short* __restrict__ w4t,
                            unsigned short* __restrict__ w1t,
                            unsigned short* __restrict__ w3t) {
    int idx = blockIdx.x * 256 + threadIdx.x;
    if (idx < 32768) {
        int n = idx >> 7, k = idx & 127;
        w4t[idx] = f2bfu(W4[k * 256 + n]);
    } else if (idx < 32768 + 32 * 352) {
        int j = idx - 32768;
        int ch = j / 352, k = j - ch * 352;
        w1t[j] = (k < 350) ? f2bfu(W1[k * 32 + ch]) : 0;
    } else if (idx < 32768 + 32 * 352 + 128 * 64) {
        int j = idx - (32768 + 32 * 352);
        int n = j >> 6, k = j & 63;
        w3t[j] = f2bfu(W3[k * 128 + n]);
    }
}

// ---- finalize: sum NDCOPY float copies -> per-channel scale/shift --------
template <int FO>
__global__ void finalize_kernel(const float* __restrict__ ds,
                                const float* __restrict__ dq,
                                const float* __restrict__ g,
                                const float* __restrict__ be,
                                float* __restrict__ aS, float* __restrict__ cS,
                                int C) {
    int ch = threadIdx.x;
    if (ch < FO) {
        float s = 0.f, q = 0.f;
        #pragma unroll
        for (int k = 0; k < NDCOPY; ++k) {
            s += ds[(size_t)k * DSTRIDE + ch];
            q += dq[(size_t)k * DSTRIDE + ch];
        }
        double m = (double)s / (double)C;
        double v = (double)q / (double)C - m * m;
        float rs = rsqrtf((float)v + BN_EPS);
        float a = g[ch] * rs;
        aS[ch] = a;
        cS[ch] = be[ch] - (float)m * a;
    }
}

// ---- scan_sb: 1-block exclusive prefix over the 1568 sub-bucket sizes ----
__global__ __launch_bounds__(256) void scan_sb(
    const int* __restrict__ sbsize, int* __restrict__ sboff,
    int* __restrict__ sbcur, int* __restrict__ bcur,
    int nsbtot, int nsb, int N) {
    __shared__ int sc[256];
    int tid = threadIdx.x;
    int base = tid * 8;
    int v[8];
    int tsum = 0;
    #pragma unroll
    for (int e = 0; e < 8; ++e) {
        int i = base + e;
        v[e] = (i < nsbtot) ? sbsize[i] : 0;
        tsum += v[e];
    }
    sc[tid] = tsum;
    __syncthreads();
    for (int d = 1; d < 256; d <<= 1) {
        int t = (tid >= d) ? sc[tid - d] : 0;
        __syncthreads();
        sc[tid] += t;
        __syncthreads();
    }
    int run = sc[tid] - tsum;
    #pragma unroll
    for (int e = 0; e < 8; ++e) {
        int i = base + e;
        if (i < nsbtot) { sboff[i] = run; sbcur[i] = run; }
        run += v[e];
    }
    if (tid == 0) sboff[nsbtot] = N;
    __syncthreads();
    if (tid < 8) bcur[tid] = (tid * nsb < nsbtot) ? sboff[tid * nsb] : N;
}

// ---- Pass A --------------------------------------------------------------
__global__ __launch_bounds__(256) void bucketA_kernel(
    const int* __restrict__ ccids, const float* __restrict__ feat,
    int* __restrict__ bcur, i32x4* __restrict__ bstage, int N, int cg) {
    __shared__ int scnt[8], scur[8];
    int tid = threadIdx.x;
    int base = blockIdx.x * ACHUNK;
    if (tid < 8) scnt[tid] = 0;
    __syncthreads();
    int myg[8], myloc[8];
    #pragma unroll
    for (int k = 0; k < 8; ++k) {
        int i = base + k * 256 + tid;
        int g = -1, loc = 0;
        if (i < N) {
            int c = ccids[i];
            g = c / cg;
            loc = c - g * cg;
            atomicAdd(&scnt[g], 1);
        }
        myg[k] = g; myloc[k] = loc;
    }
    __syncthreads();
    if (tid < 8) scur[tid] = atomicAdd(&bcur[tid], scnt[tid]);
    __syncthreads();
    #pragma unroll
    for (int k = 0; k < 8; ++k) {
        int i = base + k * 256 + tid;
        if (i < N) {
            const float* fp = &feat[(size_t)i * 5];
            float f0 = fp[0], f1 = fp[1], f2 = fp[2], f3 = fp[3], f4 = fp[4];
            int slot = atomicAdd(&scur[myg[k]], 1);
            i32x4 r;
            r[0] = i;
            r[1] = (int)(((unsigned)f2bfu(f0)) | (((unsigned)f2bfu(f1)) << 16));
            r[2] = (int)(((unsigned)f2bfu(f2)) | (((unsigned)f2bfu(f3)) << 16));
            r[3] = (int)(((unsigned)f2bfu(f4)) | (((unsigned)myloc[k]) << 16));
            bstage[slot] = r;
        }
    }
}

// ---- Pass B2 -------------------------------------------------------------
__global__ __launch_bounds__(256) void bucketB2_kernel(
    const i32x4* __restrict__ bstage, const int* __restrict__ sboff,
    int* __restrict__ sbcur, i32x4* __restrict__ bstage2,
    int N, int C, int cg, int nsb) {
    __shared__ int scntA[256];
    __shared__ int spref[256];
    __shared__ int scur[256];
    __shared__ int sgbase[256];
    __shared__ unsigned char sbof[BCHUNK];
    __shared__ i32x4 stage2[BCHUNK];
    int tid = threadIdx.x;
    int g  = blockIdx.x & 7;
    int k  = blockIdx.x >> 3;
    int nk = gridDim.x >> 3;
    int bs = sboff[g * nsb];
    int be = sboff[(g + 1) * nsb];
    for (int cbase = bs + k * BCHUNK; cbase < be; cbase += nk * BCHUNK) {
        int cnt_ = min(BCHUNK, be - cbase);
        scntA[tid] = 0;
        __syncthreads();
        i32x4 it[8]; int sb[8];
        #pragma unroll
        for (int u = 0; u < 8; ++u) {
            int t = u * 256 + tid;
            sb[u] = -1;
            if (t < cnt_) {
                it[u] = bstage[cbase + t];
                int loc = (int)(((unsigned)it[u][3]) >> 16);
                sb[u] = loc >> 7;
                atomicAdd(&scntA[sb[u]], 1);
            }
        }
        __syncthreads();
        spref[tid] = scntA[tid];
        __syncthreads();
        for (int d = 1; d < 256; d <<= 1) {
            int t = (tid >= d) ? spref[tid - d] : 0;
            __syncthreads();
            spref[tid] += t;
            __syncthreads();
        }
        int excl = spref[tid] - scntA[tid];
        __syncthreads();
        spref[tid] = excl;
        scur[tid] = 0;
        if (tid < nsb && scntA[tid] > 0)
            sgbase[tid] = atomicAdd(&sbcur[g * nsb + tid], scntA[tid]);
        __syncthreads();
        #pragma unroll
        for (int u = 0; u < 8; ++u) {
            if (sb[u] >= 0) {
                int w = atomicAdd(&scur[sb[u]], 1);
                int pos = spref[sb[u]] + w;
                stage2[pos] = it[u];
                sbof[pos] = (unsigned char)sb[u];
            }
        }
        __syncthreads();
        for (int t = tid; t < cnt_; t += 256) {
            int s = sbof[t];
            bstage2[sgbase[s] + (t - spref[s])] = stage2[t];
        }
        __syncthreads();
    }
}

// ---- Pass C: comp-order permute + deterministic rank + cnt/off writes ----
__global__ __launch_bounds__(256) void bucketC_kernel(
    const i32x4* __restrict__ bstage2, const int* __restrict__ sboff,
    i32x4* __restrict__ srec, int* __restrict__ cnt, int* __restrict__ off,
    int N, int C, int cg, int nsb) {
    int g  = blockIdx.x >> 8;       // grid = 8 * 256
    int sb = blockIdx.x & 255;
    if (sb >= nsb) return;
    int c0 = g * cg + sb * 128;
    if (c0 >= C) return;
    int gend = min(g * cg + cg, C);
    int c1 = min(c0 + 128, gend);
    int nc = c1 - c0;
    int gsb = g * nsb + sb;
    int p0 = sboff[gsb];
    int p1 = sboff[gsb + 1];
    int count = p1 - p0;
    int tid = threadIdx.x;
    __shared__ i32x4 stg[CCAP];
    __shared__ int ccnt[128], cpref[128], ccur[128];
    if (count <= CCAP) {
        if (tid < 128) ccnt[tid] = 0;
        __syncthreads();
        for (int t = tid; t < count; t += 256) {
            int loc = (int)(((unsigned)bstage2[p0 + t][3]) >> 16);
            atomicAdd(&ccnt[loc - sb * 128], 1);
        }
        __syncthreads();
        if (tid < 128) cpref[tid] = ccnt[tid];
        __syncthreads();
        for (int d = 1; d < 128; d <<= 1) {
            int t = (tid >= d && tid < 128) ? cpref[tid - d] : 0;
            __syncthreads();
            if (tid < 128) cpref[tid] += t;
            __syncthreads();
        }
        if (tid < 128) { cpref[tid] -= ccnt[tid]; ccur[tid] = 0; }
        __syncthreads();
        if (tid < nc) {
            cnt[c0 + tid] = ccnt[tid];
            off[c0 + tid] = p0 + cpref[tid];
        }
        for (int t = tid; t < count; t += 256) {
            i32x4 r = bstage2[p0 + t];
            int cl = (int)(((unsigned)r[3]) >> 16) - sb * 128;
            int w = atomicAdd(&ccur[cl], 1);
            stg[cpref[cl] + w] = r;
        }
        __syncthreads();
        for (int t = tid; t < count; t += 256) {
            i32x4 r = stg[t];
            int cl = (int)(((unsigned)r[3]) >> 16) - sb * 128;
            int b0 = cpref[cl], cn = ccnt[cl];
            int my = r[0];
            int rk = 0;
            for (int j = 0; j < cn; ++j)
                rk += (stg[b0 + j][0] < my) ? 1 : 0;
            srec[p0 + b0 + rk] = r;
        }
    } else {
        for (int cl = tid; cl < nc; cl += 256) {
            int myloc = sb * 128 + cl;
            int cc = 0, bb = 0;
            for (int j = 0; j < count; ++j) {
                int ol = (int)(((unsigned)bstage2[p0 + j][3]) >> 16);
                cc += (ol == myloc) ? 1 : 0;
                bb += (ol < myloc) ? 1 : 0;
            }
            cnt[c0 + cl] = cc;
            off[c0 + cl] = p0 + bb;
        }
        for (int t = tid; t < count; t += 256) {
            i32x4 r = bstage2[p0 + t];
            int myloc = (int)(((unsigned)r[3]) >> 16);
            int my = r[0];
            int rk = 0, base = 0;
            for (int j = 0; j < count; ++j) {
                i32x4 o = bstage2[p0 + j];
                int ol = (int)(((unsigned)o[3]) >> 16);
                if (ol == myloc) rk += (o[0] < my) ? 1 : 0;
                else if (ol < myloc) base += 1;
            }
            srec[p0 + base + rk] = r;
        }
    }
}

// --- stage 2a: pack + MFMA GEMM 350->32 + spread BN1 stats (bf16 z1 out) --
__global__ __launch_bounds__(256) void layer1_mfma(
    const i32x4* __restrict__ srec, const int* __restrict__ cnt,
    const int* __restrict__ off,
    const unsigned short* __restrict__ w1t, const float* __restrict__ b1,
    __hip_bfloat16* __restrict__ z1, float* __restrict__ dsum,
    float* __restrict__ dsq, int C) {
    __shared__ unsigned short xtile[4][16][KPAD];
    __shared__ float sps[4][32], spq[4][32];
    int tid  = threadIdx.x;
    int w    = tid >> 6;
    int lane = tid & 63;
    int cbase = blockIdx.x * 64 + w * 16;

    unsigned int* xz = (unsigned int*)&xtile[w][0][0];
    for (int t = lane; t < 16 * (KPAD / 2); t += 64) xz[t] = 0u;

    int myc = 0, myo = 0;
    {
        int comp = cbase + (lane & 15);
        if (comp < C) { myc = cnt[comp]; myo = off[comp]; }
    }
    int fl[16], bs[16];
    #pragma unroll
    for (int s = 0; s < 16; ++s) {
        fl[s] = __shfl(myc, s);
        bs[s] = __shfl(myo, s);
    }
    __syncthreads();
    #pragma unroll
    for (int s = 0; s < 16; ++s) {
        int lim = min(fl[s], MAX_K);
        for (int e = lane; e < lim; e += 64) {
            i32x4 r = srec[bs[s] + e];
            unsigned short* xp = &xtile[w][s][e * 5];
            unsigned int y1 = (unsigned int)r[1];
            unsigned int y2 = (unsigned int)r[2];
            unsigned int y3 = (unsigned int)r[3];
            xp[0] = (unsigned short)(y1 & 0xffff);
            xp[1] = (unsigned short)(y1 >> 16);
            xp[2] = (unsigned short)(y2 & 0xffff);
            xp[3] = (unsigned short)(y2 >> 16);
            xp[4] = (unsigned short)(y3 & 0xffff);
        }
    }
    __syncthreads();

    int l15 = lane & 15, l4 = lane >> 4;
    f32x4 acc0 = {0.f, 0.f, 0.f, 0.f};
    f32x4 acc1 = {0.f, 0.f, 0.f, 0.f};
    const unsigned short* xbase = &xtile[w][l15][0];
    #pragma unroll
    for (int ks = 0; ks < 11; ++ks) {
        int k0 = ks * 32 + l4 * 8;
        bf16x8 a  = *(const bf16x8*)&xbase[k0];
        bf16x8 b0 = *(const bf16x8*)&w1t[(size_t)l15 * 352 + k0];
        bf16x8 bv = *(const bf16x8*)&w1t[(size_t)(16 + l15) * 352 + k0];
        acc0 = __builtin_amdgcn_mfma_f32_16x16x32_bf16(a, b0, acc0, 0, 0, 0);
        acc1 = __builtin_amdgcn_mfma_f32_16x16x32_bf16(a, bv, acc1, 0, 0, 0);
    }
    float bias0 = b1[l15];
    float bias1 = b1[16 + l15];
    float s0 = 0.f, q0 = 0.f, s1 = 0.f, q1 = 0.f;
    #pragma unroll
    for (int r = 0; r < 4; ++r) {
        int comp = cbase + l4 * 4 + r;
        if (comp < C) {
            float z0 = acc0[r] + bias0;
            float z1v = acc1[r] + bias1;
            storev(z1, (size_t)comp * 32 + l15, z0);
            storev(z1, (size_t)comp * 32 + 16 + l15, z1v);
            s0 += z0; q0 += z0 * z0;
            s1 += z1v; q1 += z1v * z1v;
        }
    }
    s0 += __shfl_xor(s0, 16); s0 += __shfl_xor(s0, 32);
    q0 += __shfl_xor(q0, 16); q0 += __shfl_xor(q0, 32);
    s1 += __shfl_xor(s1, 16); s1 += __shfl_xor(s1, 32);
    q1 += __shfl_xor(q1, 16); q1 += __shfl_xor(q1, 32);
    if (lane < 16) {
        sps[w][l15] = s0;      spq[w][l15] = q0;
        sps[w][16 + l15] = s1; spq[w][16 + l15] = q1;
    }
    __syncthreads();
    if (tid < 32) {
        float s = sps[0][tid] + sps[1][tid] + sps[2][tid] + sps[3][tid];
        float q = spq[0][tid] + spq[1][tid] + spq[2][tid] + spq[3][tid];
        size_t cb = (size_t)(blockIdx.x & (NDCOPY - 1)) * DSTRIDE;
        unsafeAtomicAdd(&dsum[cb + tid], s);
        unsafeAtomicAdd(&dsq[cb + tid],  q);
    }
}

// ---- generic layer (used for layer2): aS/cS in, spread float stats out ---
template <typename TI, typename TO, int FI, int FO, int CT, int RT>
__global__ __launch_bounds__(256) void layer_kernel(
    const TI* __restrict__ zin, const float* __restrict__ W,
    const float* __restrict__ bias,
    const float* __restrict__ aS, const float* __restrict__ cS,
    TO* __restrict__ zout,
    float* __restrict__ dsO, float* __restrict__ dqO, int C) {
    constexpr int CHG  = FO / CT;
    constexpr int NSUB = 256 / CHG;
    constexpr int R    = NSUB * RT;
    __shared__ float h[R][FI + 1];
    __shared__ float sps[NSUB * FO];
    __shared__ float spq[NSUB * FO];
    __shared__ float aSs[FI], cSs[FI];
    int tid = threadIdx.x;
    int c0 = blockIdx.x * R;
    if (tid < FI) { aSs[tid] = aS[tid]; cSs[tid] = cS[tid]; }
    __syncthreads();
    for (int t = tid; t < R * FI; t += 256) {
        int r = t / FI, k = t % FI;
        int c = c0 + r;
        float v = (c < C) ? loadv(zin, (size_t)c * FI + k) : 0.f;
        h[r][k] = fmaxf(fmaf(aSs[k], v, cSs[k]), 0.f);
    }
    __syncthreads();
    int cg  = tid % CHG;
    int sub = tid / CHG;
    int chbase = cg * CT;
    float acc[RT][CT];
    #pragma unroll
    for (int i = 0; i < RT; ++i)
        #pragma unroll
        for (int j = 0; j < CT; ++j) acc[i][j] = 0.f;
    for (int k = 0; k < FI; ++k) {
        float wv[CT];
        #pragma unroll
        for (int j4 = 0; j4 < CT; j4 += 4) {
            const float4 wq = *reinterpret_cast<const float4*>(
                &W[(size_t)k * FO + chbase + j4]);
            wv[j4 + 0] = wq.x; wv[j4 + 1] = wq.y;
            wv[j4 + 2] = wq.z; wv[j4 + 3] = wq.w;
        }
        #pragma unroll
        for (int i = 0; i < RT; ++i) {
            float hv = h[sub * RT + i][k];
            #pragma unroll
            for (int j = 0; j < CT; ++j) acc[i][j] = fmaf(hv, wv[j], acc[i][j]);
        }
    }
    float ps[CT], pq[CT];
    #pragma unroll
    for (int j = 0; j < CT; ++j) { ps[j] = 0.f; pq[j] = 0.f; }
    #pragma unroll
    for (int i = 0; i < RT; ++i) {
        int c = c0 + sub * RT + i;
        if (c < C) {
            #pragma unroll
            for (int j = 0; j < CT; ++j) {
                float z = acc[i][j] + bias[chbase + j];
                storev(zout, (size_t)c * FO + chbase + j, z);
                ps[j] += z;
                pq[j] += z * z;
            }
        }
    }
    #pragma unroll
    for (int j = 0; j < CT; ++j) {
        sps[sub * FO + chbase + j] = ps[j];
        spq[sub * FO + chbase + j] = pq[j];
    }
    __syncthreads();
    if (tid < FO) {
        float s = 0.f, q = 0.f;
        #pragma unroll
        for (int s2 = 0; s2 < NSUB; ++s2) {
            s += sps[s2 * FO + tid];
            q += spq[s2 * FO + tid];
        }
        size_t cb = (size_t)(blockIdx.x & (NDCOPY - 1)) * DSTRIDE;
        unsafeAtomicAdd(&dsO[cb + tid], s);
        unsafeAtomicAdd(&dqO[cb + tid], q);
    }
}

// --- layer 3 via MFMA: K=64, N=128; A-in-regs, swizzled LDS stage ---------
__global__ __launch_bounds__(256, 3) void layer3_mfma(
    const __hip_bfloat16* __restrict__ z2, const unsigned short* __restrict__ w3t,
    const float* __restrict__ b3,
    const float* __restrict__ aS, const float* __restrict__ cS,
    __hip_bfloat16* __restrict__ z3,
    float* __restrict__ dsum, float* __restrict__ dsq, int C) {
    __shared__ unsigned short tile[64 * 128];   // 16 KB output stage
    __shared__ float sps[2][128];
    __shared__ float spq[2][128];
    __shared__ float aSs[64], cSs[64];
    int tid = threadIdx.x, wid = tid >> 6, lane = tid & 63;
    int wm = wid >> 1, wn = wid & 1;
    int c0 = blockIdx.x * 64;
    int l15 = lane & 15, l4 = lane >> 4;
    const unsigned short* z2u = (const unsigned short*)z2;
    if (tid < 64) { aSs[tid] = aS[tid]; cSs[tid] = cS[tid]; }
    __syncthreads();

    bf16x8 afrag[2][2];
    int rowA0 = c0 + wm * 32 + l15;
    #pragma unroll
    for (int ks = 0; ks < 2; ++ks) {
        int k0 = ks * 32 + l4 * 8;
        #pragma unroll
        for (int mi = 0; mi < 2; ++mi) {
            int r = rowA0 + mi * 16;
            int rc = (r < C) ? r : (C - 1);
            bf16x8 raw = *(const bf16x8*)&z2u[(size_t)rc * 64 + k0];
            bf16x8 af;
            #pragma unroll
            for (int j = 0; j < 8; ++j) {
                float v = bf2f((unsigned short)raw[j]);
                float hx = fmaxf(fmaf(aSs[k0 + j], v, cSs[k0 + j]), 0.f);
                af[j] = (short)f2bfu((r < C) ? hx : 0.f);
            }
            afrag[mi][ks] = af;
        }
    }

    f32x4 acc[2][4];
    #pragma unroll
    for (int mi = 0; mi < 2; ++mi)
        #pragma unroll
        for (int ni = 0; ni < 4; ++ni)
            acc[mi][ni] = (f32x4){0.f, 0.f, 0.f, 0.f};
    #pragma unroll
    for (int ks = 0; ks < 2; ++ks) {
        int k0 = ks * 32 + l4 * 8;
        bf16x8 bfrag[4];
        #pragma unroll
        for (int ni = 0; ni < 4; ++ni) {
            int n = wn * 64 + ni * 16 + l15;
            bfrag[ni] = *(const bf16x8*)&w3t[(size_t)n * 64 + k0];
        }
        #pragma unroll
        for (int mi = 0; mi < 2; ++mi)
            #pragma unroll
            for (int ni = 0; ni < 4; ++ni)
                acc[mi][ni] = __builtin_amdgcn_mfma_f32_16x16x32_bf16(
                    afrag[mi][ks], bfrag[ni], acc[mi][ni], 0, 0, 0);
    }
    #pragma unroll
    for (int ni = 0; ni < 4; ++ni) {
        int col = wn * 64 + ni * 16 + l15;
        float bv = b3[col];
        float s = 0.f, q = 0.f;
        #pragma unroll
        for (int mi = 0; mi < 2; ++mi) {
            #pragma unroll
            for (int r = 0; r < 4; ++r) {
                int lrow = wm * 32 + mi * 16 + l4 * 4 + r;
                float z = acc[mi][ni][r] + bv;
                int sc = (col & 7) + 8 * ((col >> 3) ^ ((lrow >> 2) & 7));
                tile[lrow * 128 + sc] = f2bfu(z);
                if (c0 + lrow < C) { s += z; q += z * z; }
            }
        }
        s += __shfl_xor(s, 16); s += __shfl_xor(s, 32);
        q += __shfl_xor(q, 16); q += __shfl_xor(q, 32);
        if (lane < 16) { sps[wm][col] = s; spq[wm][col] = q; }
    }
    __syncthreads();
    if (tid < 128) {
        float s = sps[0][tid] + sps[1][tid];
        float q = spq[0][tid] + spq[1][tid];
        size_t cb = (size_t)(blockIdx.x & (NDCOPY - 1)) * DSTRIDE;
        unsafeAtomicAdd(&dsum[cb + tid], s);
        unsafeAtomicAdd(&dsq[cb + tid],  q);
    }
    unsigned short* z3u = (unsigned short*)z3;
    #pragma unroll
    for (int k = 0; k < 4; ++k) {
        int ch = k * 256 + tid;          // 1024 chunks of 16B
        int lrow = ch >> 4;              // 16 chunks per 256B row
        int c8 = ch & 15;
        if (c0 + lrow < C)
            *(bf16x8*)&z3u[(size_t)(c0 + lrow) * 128 + c8 * 8] =
                *(bf16x8*)&tile[lrow * 128 + 8 * (c8 ^ ((lrow >> 2) & 7))];
    }
}

// --- layer 4 via MFMA: A-in-regs, HALF-TILE staging (16KB) for occupancy --
__global__ __launch_bounds__(256, 4) void layer4_mfma(
    const __hip_bfloat16* __restrict__ z3, const unsigned short* __restrict__ w4t,
    const float* __restrict__ b4,
    const float* __restrict__ aS, const float* __restrict__ cS,
    __hip_bfloat16* __restrict__ z4,
    float* __restrict__ dsum, float* __restrict__ dsq, int C) {
    __shared__ unsigned short tile[64 * 128];   // 16 KB per-half stage
    __shared__ float sps[2][256];
    __shared__ float spq[2][256];
    __shared__ float aSs[128], cSs[128];
    int tid = threadIdx.x, wid = tid >> 6, lane = tid & 63;
    int wm = wid >> 1, wn = wid & 1;
    int c0 = blockIdx.x * 64;
    int l15 = lane & 15, l4 = lane >> 4;
    const unsigned short* z3u = (const unsigned short*)z3;
    if (tid < 128) { aSs[tid] = aS[tid]; cSs[tid] = cS[tid]; }
    __syncthreads();

    bf16x8 afrag[2][4];
    int rowA0 = c0 + wm * 32 + l15;
    #pragma unroll
    for (int ks = 0; ks < 4; ++ks) {
        int k0 = ks * 32 + l4 * 8;
        #pragma unroll
        for (int mi = 0; mi < 2; ++mi) {
            int r = rowA0 + mi * 16;
            int rc = (r < C) ? r : (C - 1);
            bf16x8 raw = *(const bf16x8*)&z3u[(size_t)rc * 128 + k0];
            bf16x8 af;
            #pragma unroll
            for (int j = 0; j < 8; ++j) {
                float v = bf2f((unsigned short)raw[j]);
                float hx = fmaxf(fmaf(aSs[k0 + j], v, cSs[k0 + j]), 0.f);
                af[j] = (short)f2bfu((r < C) ? hx : 0.f);
            }
            afrag[mi][ks] = af;
        }
    }

    unsigned short* z4u = (unsigned short*)z4;
    #pragma unroll
    for (int nh = 0; nh < 2; ++nh) {
        f32x4 acc[2][4];
        #pragma unroll
        for (int mi = 0; mi < 2; ++mi)
            #pragma unroll
            for (int ni = 0; ni < 4; ++ni)
                acc[mi][ni] = (f32x4){0.f, 0.f, 0.f, 0.f};
        #pragma unroll
        for (int ks = 0; ks < 4; ++ks) {
            int k0 = ks * 32 + l4 * 8;
            bf16x8 bfrag[4];
            #pragma unroll
            for (int ni = 0; ni < 4; ++ni) {
                int n = wn * 128 + nh * 64 + ni * 16 + l15;
                bfrag[ni] = *(const bf16x8*)&w4t[(size_t)n * 128 + k0];
            }
            #pragma unroll
            for (int mi = 0; mi < 2; ++mi)
                #pragma unroll
                for (int ni = 0; ni < 4; ++ni)
                    acc[mi][ni] = __builtin_amdgcn_mfma_f32_16x16x32_bf16(
                        afrag[mi][ks], bfrag[ni], acc[mi][ni], 0, 0, 0);
        }
        // epilogue half: bias, stats, stage into 64x128 tile.
        // local column lc = (wn*128 + nh*64 + ni*16 + l15) - half base.
        #pragma unroll
        for (int ni = 0; ni < 4; ++ni) {
            int col = wn * 128 + nh * 64 + ni * 16 + l15;   // global col
            int lc  = (wn * 64 + ni * 16 + l15);            // 0..127 in half
            float bv = b4[col];
            float s = 0.f, q = 0.f;
            #pragma unroll
            for (int mi = 0; mi < 2; ++mi) {
                #pragma unroll
                for (int r = 0; r < 4; ++r) {
                    int lrow = wm * 32 + mi * 16 + l4 * 4 + r;
                    float z = acc[mi][ni][r] + bv;
                    int sc = (lc & 7) + 8 * ((lc >> 3) ^ ((lrow >> 2) & 7));
                    tile[lrow * 128 + sc] = f2bfu(z);
                    if (c0 + lrow < C) { s += z; q += z * z; }
                }
            }
            s += __shfl_xor(s, 16); s += __shfl_xor(s, 32);
            q += __shfl_xor(q, 16); q += __shfl_xor(q, 32);
            if (lane < 16) { sps[wm][col] = s; spq[wm][col] = q; }
        }
        __syncthreads();  // tile writes visible
        // drain half: columns [half*128, half*128+128)
        // wn halves of the tile columns map: local col lc -> global nh*?? ...
        // NOTE: waves with wn=0 wrote lc 0..63, wn=1 wrote lc 64..127; the
        // half's global column base is: gcolbase(lc) = (lc<64 ? 0:64) + nh*?? 
        // Global col = wn*128 + nh*64 + (lc - wn*64). Drain must invert:
        // for chunk lc8 in 0..15: lc = lc8*8.. ; gcol = (lc<64?0:128) ... 
        #pragma unroll
        for (int k = 0; k < 4; ++k) {
            int ch = k * 256 + tid;      // 1024 chunks of 16B
            int lrow = ch >> 4;          // 16 chunks per 128-col row
            int c8 = ch & 15;            // local chunk 0..15 -> lc = c8*8
            int lc = c8 * 8;
            int gcol = (lc < 64 ? 0 : 128) + nh * 64 + (lc & 63);
            if (c0 + lrow < C)
                *(bf16x8*)&z4u[(size_t)(c0 + lrow) * 256 + gcol] =
                    *(bf16x8*)&tile[lrow * 128 + 8 * (c8 ^ ((lrow >> 2) & 7))];
        }
        __syncthreads();  // tile reads done before next half overwrites
    }
    if (tid < 256) {
        float s = sps[0][tid] + sps[1][tid];
        float q = spq[0][tid] + spq[1][tid];
        size_t cb = (size_t)(blockIdx.x & (NDCOPY - 1)) * DSTRIDE;
        unsafeAtomicAdd(&dsum[cb + tid], s);
        unsafeAtomicAdd(&dsq[cb + tid],  q);
    }
}

// -- segment-sum of relu(bn4(z4)): precomputed aS/cS -----------------------
__global__ __launch_bounds__(256) void pool_kernel(
    const __hip_bfloat16* __restrict__ z4, const int* __restrict__ imgid,
    const float* __restrict__ aS, const float* __restrict__ cS,
    float* __restrict__ pool, int C, int B) {
    __shared__ float spool[64 * 256];
    int tid = threadIdx.x;
    int nb = B * 256;
    for (int t = tid; t < nb; t += 256) spool[t] = 0.f;
    __syncthreads();
    float a = aS[tid], cc = cS[tid];
    int per  = (C + gridDim.x - 1) / gridDim.x;
    int cbeg = blockIdx.x * per;
    int cend = min(cbeg + per, C);
    int c = cbeg;
    for (; c + 16 <= cend; c += 16) {
        float v[16];
        int im[16];
        #pragma unroll
        for (int u = 0; u < 16; ++u) {
            im[u] = imgid[c + u];
            v[u] = loadv(z4, (size_t)(c + u) * 256 + tid);
        }
        #pragma unroll
        for (int u = 0; u < 16; ++u) {
            float hv = fmaxf(fmaf(a, v[u], cc), 0.f);
            spool[im[u] * 256 + tid] += hv;
        }
    }
    for (; c < cend; ++c) {
        int img = imgid[c];
        float v = loadv(z4, (size_t)c * 256 + tid);
        float hv = fmaxf(fmaf(a, v, cc), 0.f);
        spool[img * 256 + tid] += hv;
    }
    __syncthreads();
    float* dst = pool + (size_t)(blockIdx.x & (NPOOL - 1)) * nb;
    int start = ((int)blockIdx.x * 2048) % nb;
    for (int t0 = 0; t0 < nb; t0 += 256) {
        int t = (start + t0 + tid) % nb;
        unsafeAtomicAdd(&dst[t], spool[t]);
    }
}

// ---------- mean over comps (sum NPOOL copies), BN over 64 image rows -----
__global__ void bn5_kernel(const float* __restrict__ pool,
                           const int* __restrict__ pcnt,
                           const float* __restrict__ g5,
                           const float* __restrict__ be5,
                           float* __restrict__ y, int B) {
    int ch = threadIdx.x;
    int nb = B * 256;
    double s = 0.0, s2 = 0.0;
    float vals[64];
    for (int b = 0; b < B; ++b) {
        float v = 0.f;
        #pragma unroll
        for (int k = 0; k < NPOOL; ++k) v += pool[k * nb + b * 256 + ch];
        float c = (float)pcnt[b]; if (c < 1.f) c = 1.f;
        v /= c;
        vals[b] = v;
        s += (double)v; s2 += (double)v * (double)v;
    }
    double m = s / (double)B;
    double var = s2 / (double)B - m * m;
    float rs = rsqrtf((float)var + BN_EPS);
    float a = g5[ch] * rs;
    float cc = be5[ch] - (float)m * a;
    for (int b = 0; b < B; ++b)
        y[b * 256 + ch] = fmaf(a, vals[b], cc);
}

// ------------------------------------------------------- final FC + ReLU
__global__ __launch_bounds__(256) void fc_kernel(
    const float* __restrict__ y, const float* __restrict__ Wfc,
    const float* __restrict__ bfc, float* __restrict__ out, int NC) {
    int b = blockIdx.y;
    int ch = blockIdx.x * 256 + threadIdx.x;
    __shared__ float sy[256];
    sy[threadIdx.x] = y[b * 256 + threadIdx.x];
    __syncthreads();
    if (ch < NC) {
        float acc = bfc[ch];
        for (int k = 0; k < 256; ++k)
            acc = fmaf(sy[k], Wfc[(size_t)k * NC + ch], acc);
        out[(size_t)b * NC + ch] = fmaxf(acc, 0.f);
    }
}

// ---------------------------------------------------------------- launcher
extern "C" void kernel_launch(void* const* d_in, const int* in_sizes, int n_in,
                              void* d_out, int out_size, void* d_ws,
                              size_t ws_size, hipStream_t stream) {
    const float* item_feat = (const float*)d_in[0];
    const int*   ccids     = (const int*)d_in[1];
    const int*   imgid     = (const int*)d_in[2];
    const float* W1  = (const float*)d_in[3];
    const float* b1  = (const float*)d_in[4];
    const float* g1  = (const float*)d_in[5];
    const float* be1 = (const float*)d_in[6];
    const float* W2  = (const float*)d_in[7];
    const float* b2  = (const float*)d_in[8];
    const float* g2  = (const float*)d_in[9];
    const float* be2 = (const float*)d_in[10];
    const float* W3  = (const float*)d_in[11];
    const float* b3  = (const float*)d_in[12];
    const float* g3  = (const float*)d_in[13];
    const float* be3 = (const float*)d_in[14];
    const float* W4  = (const float*)d_in[15];
    const float* b4  = (const float*)d_in[16];
    const float* g4  = (const float*)d_in[17];
    const float* be4 = (const float*)d_in[18];
    const float* g5  = (const float*)d_in[19];
    const float* be5 = (const float*)d_in[20];
    const float* Wfc = (const float*)d_in[21];
    const float* bfc = (const float*)d_in[22];
    float* out = (float*)d_out;

    const int N  = in_sizes[1];
    const int C  = in_sizes[2];
    const int NC = in_sizes[22];
    const int B  = out_size / NC;

    uint8_t* ws = (uint8_t*)d_ws;
    size_t off_ = 0;
    auto alloc = [&](size_t bytes) -> void* {
        void* p = (void*)(ws + off_);
        off_ += (bytes + 255) & ~(size_t)255;
        return p;
    };
    int*    sbsize = (int*)alloc((size_t)NSBMAX * 4);
    float*  fstats = (float*)alloc((size_t)NDCOPY * DSTRIDE * 4);  // 360 KB
    int*    pcnt   = (int*)alloc((size_t)B * 4);
    float*  pool   = (float*)alloc((size_t)NPOOL * B * 256 * 4);
    size_t zeroBytes = off_;
    float*  y      = (float*)alloc((size_t)B * 256 * 4);
    float*  scales = (float*)alloc((size_t)(32 + 64 + 128 + 256) * 2 * 4);
    int*    cnt    = (int*)alloc((size_t)C * 4);
    int*    off    = (int*)alloc((size_t)C * 4);
    int*    sboff  = (int*)alloc((size_t)(NSBMAX + 1) * 4);
    int*    sbcur  = (int*)alloc((size_t)NSBMAX * 4);
    int*    bcur   = (int*)alloc((size_t)8 * 4);
    unsigned short* w4t = (unsigned short*)alloc((size_t)256 * 128 * 2);
    unsigned short* w1t = (unsigned short*)alloc((size_t)32 * 352 * 2);
    unsigned short* w3t = (unsigned short*)alloc((size_t)128 * 64 * 2);
    void* regionA = alloc((size_t)N * 16);
    void* regionB = alloc((size_t)C * 256 * 2);
    (void)ws_size;

    i32x4*           bstage  = (i32x4*)regionB;
    i32x4*           bstage2 = (i32x4*)regionA;
    i32x4*           srec    = (i32x4*)regionB;
    __hip_bfloat16*  z1      = (__hip_bfloat16*)regionA;  // C x 32 bf16
    __hip_bfloat16*  z3      = (__hip_bfloat16*)regionA;  // C x 128 bf16 (after z1)
    __hip_bfloat16*  z2      = (__hip_bfloat16*)regionB;  // C x 64 bf16
    __hip_bfloat16*  z4      = (__hip_bfloat16*)regionB;  // C x 256 bf16

    float *ds1 = fstats +   0, *dq1 = fstats +  32;
    float *ds2 = fstats +  64, *dq2 = fstats + 128;
    float *ds3 = fstats + 192, *dq3 = fstats + 320;
    float *ds4 = fstats + 448, *dq4 = fstats + 704;
    float *aS1 = scales +   0, *cS1 = scales +  32;
    float *aS2 = scales +  64, *cS2 = scales + 128;
    float *aS3 = scales + 192, *cS3 = scales + 320;
    float *aS4 = scales + 448, *cS4 = scales + 704;

    const int cg     = (C + 7) / 8;        // 25000
    const int nsb    = (cg + 127) / 128;   // 196
    const int nsbtot = 8 * nsb;            // 1568 (<= NSBMAX)

    hipMemsetAsync(ws, 0, zeroBytes, stream);
    hist_kernel<<<512, 256, 0, stream>>>((const i32x4*)ccids, sbsize,
                                         imgid, pcnt, N / 4, C, cg, nsb, B);
    prep_kernel<<<205, 256, 0, stream>>>(W4, W1, W3, w4t, w1t, w3t);
    scan_sb<<<1, 256, 0, stream>>>(sbsize, sboff, sbcur, bcur, nsbtot, nsb, N);
    bucketA_kernel<<<(N + ACHUNK - 1) / ACHUNK, 256, 0, stream>>>(
        ccids, item_feat, bcur, bstage, N, cg);
    bucketB2_kernel<<<1960, 256, 0, stream>>>(bstage, sboff, sbcur, bstage2,
                                              N, C, cg, nsb);
    bucketC_kernel<<<8 * 256, 256, 0, stream>>>(bstage2, sboff, srec,
                                                cnt, off, N, C, cg, nsb);

    layer1_mfma<<<(C + 63) / 64, 256, 0, stream>>>(srec, cnt, off,
                                                   w1t, b1, z1, ds1, dq1, C);
    finalize_kernel<32><<<1, 32, 0, stream>>>(ds1, dq1, g1, be1, aS1, cS1, C);

    layer_kernel<__hip_bfloat16, __hip_bfloat16, 32, 64, 4, 8>
        <<<(C + 127) / 128, 256, 0, stream>>>(z1, W2, b2, aS1, cS1,
                                              z2, ds2, dq2, C);
    finalize_kernel<64><<<1, 64, 0, stream>>>(ds2, dq2, g2, be2, aS2, cS2, C);

    layer3_mfma<<<(C + 63) / 64, 256, 0, stream>>>(z2, w3t, b3, aS2, cS2,
                                                   z3, ds3, dq3, C);
    finalize_kernel<128><<<1, 128, 0, stream>>>(ds3, dq3, g3, be3, aS3, cS3, C);

    layer4_mfma<<<(C + 63) / 64, 256, 0, stream>>>(z3, w4t, b4, aS3, cS3,
                                                   z4, ds4, dq4, C);
    finalize_kernel<256><<<1, 256, 0, stream>>>(ds4, dq4, g4, be4, aS4, cS4, C);

    pool_kernel<<<512, 256, 0, stream>>>(z4, imgid, aS4, cS4, pool, C, B);
    bn5_kernel<<<1, 256, 0, stream>>>(pool, pcnt, g5, be5, y, B);

    dim3 fcg((NC + 255) / 256, B);
    fc_kernel<<<fcg, 256, 0, stream>>>(y, Wfc, bfc, out, NC);
}

// Round 25
// 524.028 us; speedup vs baseline: 1.0219x; 1.0219x over previous
//
#include <hip/hip_runtime.h>
#include <hip/hip_bf16.h>
#include <cstdint>
#include <cstddef>

#define MAX_K 70
#define BN_EPS 1e-5f
#define KPAD 360
#define NPOOL 16
#define ACHUNK 2048
#define BCHUNK 2048
#define CCAP 3584   // max items per 128-comp sub-bucket staged in LDS (~13 sigma)
#define NSBMAX 2048 // LDS histogram bins (>= 8 * nsb)
#define NDCOPY 64   // BN-stat atomic spreading copies
#define DSTRIDE 1408 // floats per copy: (32+64+128+256)*2

typedef __attribute__((ext_vector_type(4))) float f32x4;
typedef __attribute__((ext_vector_type(8))) short bf16x8;
typedef __attribute__((ext_vector_type(4))) int i32x4;

__device__ inline float loadv(const float* p, size_t i) { return p[i]; }
__device__ inline float loadv(const __hip_bfloat16* p, size_t i) {
    return __bfloat162float(p[i]);
}
__device__ inline void storev(float* p, size_t i, float v) { p[i] = v; }
__device__ inline void storev(__hip_bfloat16* p, size_t i, float v) {
    p[i] = __float2bfloat16(v);
}
__device__ inline float bf2f(unsigned short u) {
    union { unsigned int i; float f; } x; x.i = ((unsigned int)u) << 16; return x.f;
}
__device__ inline unsigned short f2bfu(float f) {
    __hip_bfloat16 h = __float2bfloat16(f);
    return *reinterpret_cast<unsigned short*>(&h);
}

// ---- hist1568: LDS-aggregated sub-bucket histogram (+ fused imgcnt) ------
__global__ __launch_bounds__(256) void hist_kernel(
    const i32x4* __restrict__ cc4, int* __restrict__ sbsize,
    const int* __restrict__ imgid, int* __restrict__ pcnt,
    int n4, int C, int cg, int nsb, int B) {
    __shared__ int h[NSBMAX];
    __shared__ int scnt[64];
    int tid = threadIdx.x;
    int nsbtot = 8 * nsb;
    for (int t = tid; t < nsbtot; t += 256) h[t] = 0;
    if (tid < B) scnt[tid] = 0;
    __syncthreads();
    int per = (n4 + gridDim.x - 1) / gridDim.x;
    int q0 = blockIdx.x * per, q1 = min(q0 + per, n4);
    for (int q = q0 + tid; q < q1; q += 256) {
        i32x4 v = cc4[q];
        #pragma unroll
        for (int e = 0; e < 4; ++e) {
            int c = v[e];
            int g = c / cg;
            int loc = c - g * cg;
            atomicAdd(&h[g * nsb + (loc >> 7)], 1);
        }
    }
    for (int i = blockIdx.x * 256 + tid; i < C; i += gridDim.x * 256)
        atomicAdd(&scnt[imgid[i]], 1);
    __syncthreads();
    for (int t = tid; t < nsbtot; t += 256) {
        int v = h[t];
        if (v) atomicAdd(&sbsize[t], v);
    }
    if (tid < B) {
        int v = scnt[tid];
        if (v) atomicAdd(&pcnt[tid], v);
    }
}

// ---- weight prep: w4t[256][128], w1t[32][352], w3t[128][64] --------------
__global__ void prep_kernel(const float* __restrict__ W4,
                            const float* __restrict__ W1,
                            const float* __restrict__ W3,
                            unsigned short* __restrict__ w4t,
                            unsigned short* __restrict__ w1t,
                            unsigned short* __restrict__ w3t) {
    int idx = blockIdx.x * 256 + threadIdx.x;
    if (idx < 32768) {
        int n = idx >> 7, k = idx & 127;
        w4t[idx] = f2bfu(W4[k * 256 + n]);
    } else if (idx < 32768 + 32 * 352) {
        int j = idx - 32768;
        int ch = j / 352, k = j - ch * 352;
        w1t[j] = (k < 350) ? f2bfu(W1[k * 32 + ch]) : 0;
    } else if (idx < 32768 + 32 * 352 + 128 * 64) {
        int j = idx - (32768 + 32 * 352);
        int n = j >> 6, k = j & 63;
        w3t[j] = f2bfu(W3[k * 128 + n]);
    }
}

// ---- finalize: sum NDCOPY float copies -> per-channel scale/shift --------
template <int FO>
__global__ void finalize_kernel(const float* __restrict__ ds,
                                const float* __restrict__ dq,
                                const float* __restrict__ g,
                                const float* __restrict__ be,
                                float* __restrict__ aS, float* __restrict__ cS,
                                int C) {
    int ch = threadIdx.x;
    if (ch < FO) {
        float s = 0.f, q = 0.f;
        #pragma unroll
        for (int k = 0; k < NDCOPY; ++k) {
            s += ds[(size_t)k * DSTRIDE + ch];
            q += dq[(size_t)k * DSTRIDE + ch];
        }
        double m = (double)s / (double)C;
        double v = (double)q / (double)C - m * m;
        float rs = rsqrtf((float)v + BN_EPS);
        float a = g[ch] * rs;
        aS[ch] = a;
        cS[ch] = be[ch] - (float)m * a;
    }
}

// ---- scan_sb: 1-block exclusive prefix over the 1568 sub-bucket sizes ----
__global__ __launch_bounds__(256) void scan_sb(
    const int* __restrict__ sbsize, int* __restrict__ sboff,
    int* __restrict__ sbcur, int* __restrict__ bcur,
    int nsbtot, int nsb, int N) {
    __shared__ int sc[256];
    int tid = threadIdx.x;
    int base = tid * 8;
    int v[8];
    int tsum = 0;
    #pragma unroll
    for (int e = 0; e < 8; ++e) {
        int i = base + e;
        v[e] = (i < nsbtot) ? sbsize[i] : 0;
        tsum += v[e];
    }
    sc[tid] = tsum;
    __syncthreads();
    for (int d = 1; d < 256; d <<= 1) {
        int t = (tid >= d) ? sc[tid - d] : 0;
        __syncthreads();
        sc[tid] += t;
        __syncthreads();
    }
    int run = sc[tid] - tsum;
    #pragma unroll
    for (int e = 0; e < 8; ++e) {
        int i = base + e;
        if (i < nsbtot) { sboff[i] = run; sbcur[i] = run; }
        run += v[e];
    }
    if (tid == 0) sboff[nsbtot] = N;
    __syncthreads();
    if (tid < 8) bcur[tid] = (tid * nsb < nsbtot) ? sboff[tid * nsb] : N;
}

// ---- Pass A --------------------------------------------------------------
__global__ __launch_bounds__(256) void bucketA_kernel(
    const int* __restrict__ ccids, const float* __restrict__ feat,
    int* __restrict__ bcur, i32x4* __restrict__ bstage, int N, int cg) {
    __shared__ int scnt[8], scur[8];
    int tid = threadIdx.x;
    int base = blockIdx.x * ACHUNK;
    if (tid < 8) scnt[tid] = 0;
    __syncthreads();
    int myg[8], myloc[8];
    #pragma unroll
    for (int k = 0; k < 8; ++k) {
        int i = base + k * 256 + tid;
        int g = -1, loc = 0;
        if (i < N) {
            int c = ccids[i];
            g = c / cg;
            loc = c - g * cg;
            atomicAdd(&scnt[g], 1);
        }
        myg[k] = g; myloc[k] = loc;
    }
    __syncthreads();
    if (tid < 8) scur[tid] = atomicAdd(&bcur[tid], scnt[tid]);
    __syncthreads();
    #pragma unroll
    for (int k = 0; k < 8; ++k) {
        int i = base + k * 256 + tid;
        if (i < N) {
            const float* fp = &feat[(size_t)i * 5];
            float f0 = fp[0], f1 = fp[1], f2 = fp[2], f3 = fp[3], f4 = fp[4];
            int slot = atomicAdd(&scur[myg[k]], 1);
            i32x4 r;
            r[0] = i;
            r[1] = (int)(((unsigned)f2bfu(f0)) | (((unsigned)f2bfu(f1)) << 16));
            r[2] = (int)(((unsigned)f2bfu(f2)) | (((unsigned)f2bfu(f3)) << 16));
            r[3] = (int)(((unsigned)f2bfu(f4)) | (((unsigned)myloc[k]) << 16));
            bstage[slot] = r;
        }
    }
}

// ---- Pass B2 -------------------------------------------------------------
__global__ __launch_bounds__(256) void bucketB2_kernel(
    const i32x4* __restrict__ bstage, const int* __restrict__ sboff,
    int* __restrict__ sbcur, i32x4* __restrict__ bstage2,
    int N, int C, int cg, int nsb) {
    __shared__ int scntA[256];
    __shared__ int spref[256];
    __shared__ int scur[256];
    __shared__ int sgbase[256];
    __shared__ unsigned char sbof[BCHUNK];
    __shared__ i32x4 stage2[BCHUNK];
    int tid = threadIdx.x;
    int g  = blockIdx.x & 7;
    int k  = blockIdx.x >> 3;
    int nk = gridDim.x >> 3;
    int bs = sboff[g * nsb];
    int be = sboff[(g + 1) * nsb];
    for (int cbase = bs + k * BCHUNK; cbase < be; cbase += nk * BCHUNK) {
        int cnt_ = min(BCHUNK, be - cbase);
        scntA[tid] = 0;
        __syncthreads();
        i32x4 it[8]; int sb[8];
        #pragma unroll
        for (int u = 0; u < 8; ++u) {
            int t = u * 256 + tid;
            sb[u] = -1;
            if (t < cnt_) {
                it[u] = bstage[cbase + t];
                int loc = (int)(((unsigned)it[u][3]) >> 16);
                sb[u] = loc >> 7;
                atomicAdd(&scntA[sb[u]], 1);
            }
        }
        __syncthreads();
        spref[tid] = scntA[tid];
        __syncthreads();
        for (int d = 1; d < 256; d <<= 1) {
            int t = (tid >= d) ? spref[tid - d] : 0;
            __syncthreads();
            spref[tid] += t;
            __syncthreads();
        }
        int excl = spref[tid] - scntA[tid];
        __syncthreads();
        spref[tid] = excl;
        scur[tid] = 0;
        if (tid < nsb && scntA[tid] > 0)
            sgbase[tid] = atomicAdd(&sbcur[g * nsb + tid], scntA[tid]);
        __syncthreads();
        #pragma unroll
        for (int u = 0; u < 8; ++u) {
            if (sb[u] >= 0) {
                int w = atomicAdd(&scur[sb[u]], 1);
                int pos = spref[sb[u]] + w;
                stage2[pos] = it[u];
                sbof[pos] = (unsigned char)sb[u];
            }
        }
        __syncthreads();
        for (int t = tid; t < cnt_; t += 256) {
            int s = sbof[t];
            bstage2[sgbase[s] + (t - spref[s])] = stage2[t];
        }
        __syncthreads();
    }
}

// ---- Pass C: comp-order permute + deterministic rank + cnt/off writes ----
__global__ __launch_bounds__(256) void bucketC_kernel(
    const i32x4* __restrict__ bstage2, const int* __restrict__ sboff,
    i32x4* __restrict__ srec, int* __restrict__ cnt, int* __restrict__ off,
    int N, int C, int cg, int nsb) {
    int g  = blockIdx.x >> 8;       // grid = 8 * 256
    int sb = blockIdx.x & 255;
    if (sb >= nsb) return;
    int c0 = g * cg + sb * 128;
    if (c0 >= C) return;
    int gend = min(g * cg + cg, C);
    int c1 = min(c0 + 128, gend);
    int nc = c1 - c0;
    int gsb = g * nsb + sb;
    int p0 = sboff[gsb];
    int p1 = sboff[gsb + 1];
    int count = p1 - p0;
    int tid = threadIdx.x;
    __shared__ i32x4 stg[CCAP];
    __shared__ int ccnt[128], cpref[128], ccur[128];
    if (count <= CCAP) {
        if (tid < 128) ccnt[tid] = 0;
        __syncthreads();
        for (int t = tid; t < count; t += 256) {
            int loc = (int)(((unsigned)bstage2[p0 + t][3]) >> 16);
            atomicAdd(&ccnt[loc - sb * 128], 1);
        }
        __syncthreads();
        if (tid < 128) cpref[tid] = ccnt[tid];
        __syncthreads();
        for (int d = 1; d < 128; d <<= 1) {
            int t = (tid >= d && tid < 128) ? cpref[tid - d] : 0;
            __syncthreads();
            if (tid < 128) cpref[tid] += t;
            __syncthreads();
        }
        if (tid < 128) { cpref[tid] -= ccnt[tid]; ccur[tid] = 0; }
        __syncthreads();
        if (tid < nc) {
            cnt[c0 + tid] = ccnt[tid];
            off[c0 + tid] = p0 + cpref[tid];
        }
        for (int t = tid; t < count; t += 256) {
            i32x4 r = bstage2[p0 + t];
            int cl = (int)(((unsigned)r[3]) >> 16) - sb * 128;
            int w = atomicAdd(&ccur[cl], 1);
            stg[cpref[cl] + w] = r;
        }
        __syncthreads();
        for (int t = tid; t < count; t += 256) {
            i32x4 r = stg[t];
            int cl = (int)(((unsigned)r[3]) >> 16) - sb * 128;
            int b0 = cpref[cl], cn = ccnt[cl];
            int my = r[0];
            int rk = 0;
            for (int j = 0; j < cn; ++j)
                rk += (stg[b0 + j][0] < my) ? 1 : 0;
            srec[p0 + b0 + rk] = r;
        }
    } else {
        for (int cl = tid; cl < nc; cl += 256) {
            int myloc = sb * 128 + cl;
            int cc = 0, bb = 0;
            for (int j = 0; j < count; ++j) {
                int ol = (int)(((unsigned)bstage2[p0 + j][3]) >> 16);
                cc += (ol == myloc) ? 1 : 0;
                bb += (ol < myloc) ? 1 : 0;
            }
            cnt[c0 + cl] = cc;
            off[c0 + cl] = p0 + bb;
        }
        for (int t = tid; t < count; t += 256) {
            i32x4 r = bstage2[p0 + t];
            int myloc = (int)(((unsigned)r[3]) >> 16);
            int my = r[0];
            int rk = 0, base = 0;
            for (int j = 0; j < count; ++j) {
                i32x4 o = bstage2[p0 + j];
                int ol = (int)(((unsigned)o[3]) >> 16);
                if (ol == myloc) rk += (o[0] < my) ? 1 : 0;
                else if (ol < myloc) base += 1;
            }
            srec[p0 + base + rk] = r;
        }
    }
}

// --- stage 2a: pack + MFMA GEMM 350->32 + spread BN1 stats (bf16 z1 out) --
__global__ __launch_bounds__(256) void layer1_mfma(
    const i32x4* __restrict__ srec, const int* __restrict__ cnt,
    const int* __restrict__ off,
    const unsigned short* __restrict__ w1t, const float* __restrict__ b1,
    __hip_bfloat16* __restrict__ z1, float* __restrict__ dsum,
    float* __restrict__ dsq, int C) {
    __shared__ unsigned short xtile[4][16][KPAD];
    __shared__ float sps[4][32], spq[4][32];
    int tid  = threadIdx.x;
    int w    = tid >> 6;
    int lane = tid & 63;
    int cbase = blockIdx.x * 64 + w * 16;

    unsigned int* xz = (unsigned int*)&xtile[w][0][0];
    for (int t = lane; t < 16 * (KPAD / 2); t += 64) xz[t] = 0u;

    int myc = 0, myo = 0;
    {
        int comp = cbase + (lane & 15);
        if (comp < C) { myc = cnt[comp]; myo = off[comp]; }
    }
    int fl[16], bs[16];
    #pragma unroll
    for (int s = 0; s < 16; ++s) {
        fl[s] = __shfl(myc, s);
        bs[s] = __shfl(myo, s);
    }
    __syncthreads();
    #pragma unroll
    for (int s = 0; s < 16; ++s) {
        int lim = min(fl[s], MAX_K);
        for (int e = lane; e < lim; e += 64) {
            i32x4 r = srec[bs[s] + e];
            unsigned short* xp = &xtile[w][s][e * 5];
            unsigned int y1 = (unsigned int)r[1];
            unsigned int y2 = (unsigned int)r[2];
            unsigned int y3 = (unsigned int)r[3];
            xp[0] = (unsigned short)(y1 & 0xffff);
            xp[1] = (unsigned short)(y1 >> 16);
            xp[2] = (unsigned short)(y2 & 0xffff);
            xp[3] = (unsigned short)(y2 >> 16);
            xp[4] = (unsigned short)(y3 & 0xffff);
        }
    }
    __syncthreads();

    int l15 = lane & 15, l4 = lane >> 4;
    f32x4 acc0 = {0.f, 0.f, 0.f, 0.f};
    f32x4 acc1 = {0.f, 0.f, 0.f, 0.f};
    const unsigned short* xbase = &xtile[w][l15][0];
    #pragma unroll
    for (int ks = 0; ks < 11; ++ks) {
        int k0 = ks * 32 + l4 * 8;
        bf16x8 a  = *(const bf16x8*)&xbase[k0];
        bf16x8 b0 = *(const bf16x8*)&w1t[(size_t)l15 * 352 + k0];
        bf16x8 bv = *(const bf16x8*)&w1t[(size_t)(16 + l15) * 352 + k0];
        acc0 = __builtin_amdgcn_mfma_f32_16x16x32_bf16(a, b0, acc0, 0, 0, 0);
        acc1 = __builtin_amdgcn_mfma_f32_16x16x32_bf16(a, bv, acc1, 0, 0, 0);
    }
    float bias0 = b1[l15];
    float bias1 = b1[16 + l15];
    float s0 = 0.f, q0 = 0.f, s1 = 0.f, q1 = 0.f;
    #pragma unroll
    for (int r = 0; r < 4; ++r) {
        int comp = cbase + l4 * 4 + r;
        if (comp < C) {
            float z0 = acc0[r] + bias0;
            float z1v = acc1[r] + bias1;
            storev(z1, (size_t)comp * 32 + l15, z0);
            storev(z1, (size_t)comp * 32 + 16 + l15, z1v);
            s0 += z0; q0 += z0 * z0;
            s1 += z1v; q1 += z1v * z1v;
        }
    }
    s0 += __shfl_xor(s0, 16); s0 += __shfl_xor(s0, 32);
    q0 += __shfl_xor(q0, 16); q0 += __shfl_xor(q0, 32);
    s1 += __shfl_xor(s1, 16); s1 += __shfl_xor(s1, 32);
    q1 += __shfl_xor(q1, 16); q1 += __shfl_xor(q1, 32);
    if (lane < 16) {
        sps[w][l15] = s0;      spq[w][l15] = q0;
        sps[w][16 + l15] = s1; spq[w][16 + l15] = q1;
    }
    __syncthreads();
    if (tid < 32) {
        float s = sps[0][tid] + sps[1][tid] + sps[2][tid] + sps[3][tid];
        float q = spq[0][tid] + spq[1][tid] + spq[2][tid] + spq[3][tid];
        size_t cb = (size_t)(blockIdx.x & (NDCOPY - 1)) * DSTRIDE;
        unsafeAtomicAdd(&dsum[cb + tid], s);
        unsafeAtomicAdd(&dsq[cb + tid],  q);
    }
}

// ---- generic layer (used for layer2): aS/cS in, spread float stats out ---
template <typename TI, typename TO, int FI, int FO, int CT, int RT>
__global__ __launch_bounds__(256) void layer_kernel(
    const TI* __restrict__ zin, const float* __restrict__ W,
    const float* __restrict__ bias,
    const float* __restrict__ aS, const float* __restrict__ cS,
    TO* __restrict__ zout,
    float* __restrict__ dsO, float* __restrict__ dqO, int C) {
    constexpr int CHG  = FO / CT;
    constexpr int NSUB = 256 / CHG;
    constexpr int R    = NSUB * RT;
    __shared__ float h[R][FI + 1];
    __shared__ float sps[NSUB * FO];
    __shared__ float spq[NSUB * FO];
    __shared__ float aSs[FI], cSs[FI];
    int tid = threadIdx.x;
    int c0 = blockIdx.x * R;
    if (tid < FI) { aSs[tid] = aS[tid]; cSs[tid] = cS[tid]; }
    __syncthreads();
    for (int t = tid; t < R * FI; t += 256) {
        int r = t / FI, k = t % FI;
        int c = c0 + r;
        float v = (c < C) ? loadv(zin, (size_t)c * FI + k) : 0.f;
        h[r][k] = fmaxf(fmaf(aSs[k], v, cSs[k]), 0.f);
    }
    __syncthreads();
    int cg  = tid % CHG;
    int sub = tid / CHG;
    int chbase = cg * CT;
    float acc[RT][CT];
    #pragma unroll
    for (int i = 0; i < RT; ++i)
        #pragma unroll
        for (int j = 0; j < CT; ++j) acc[i][j] = 0.f;
    for (int k = 0; k < FI; ++k) {
        float wv[CT];
        #pragma unroll
        for (int j4 = 0; j4 < CT; j4 += 4) {
            const float4 wq = *reinterpret_cast<const float4*>(
                &W[(size_t)k * FO + chbase + j4]);
            wv[j4 + 0] = wq.x; wv[j4 + 1] = wq.y;
            wv[j4 + 2] = wq.z; wv[j4 + 3] = wq.w;
        }
        #pragma unroll
        for (int i = 0; i < RT; ++i) {
            float hv = h[sub * RT + i][k];
            #pragma unroll
            for (int j = 0; j < CT; ++j) acc[i][j] = fmaf(hv, wv[j], acc[i][j]);
        }
    }
    float ps[CT], pq[CT];
    #pragma unroll
    for (int j = 0; j < CT; ++j) { ps[j] = 0.f; pq[j] = 0.f; }
    #pragma unroll
    for (int i = 0; i < RT; ++i) {
        int c = c0 + sub * RT + i;
        if (c < C) {
            #pragma unroll
            for (int j = 0; j < CT; ++j) {
                float z = acc[i][j] + bias[chbase + j];
                storev(zout, (size_t)c * FO + chbase + j, z);
                ps[j] += z;
                pq[j] += z * z;
            }
        }
    }
    #pragma unroll
    for (int j = 0; j < CT; ++j) {
        sps[sub * FO + chbase + j] = ps[j];
        spq[sub * FO + chbase + j] = pq[j];
    }
    __syncthreads();
    if (tid < FO) {
        float s = 0.f, q = 0.f;
        #pragma unroll
        for (int s2 = 0; s2 < NSUB; ++s2) {
            s += sps[s2 * FO + tid];
            q += spq[s2 * FO + tid];
        }
        size_t cb = (size_t)(blockIdx.x & (NDCOPY - 1)) * DSTRIDE;
        unsafeAtomicAdd(&dsO[cb + tid], s);
        unsafeAtomicAdd(&dqO[cb + tid], q);
    }
}

// --- layer 3 via MFMA: K=64, N=128; A-in-regs, swizzled LDS stage ---------
__global__ __launch_bounds__(256, 3) void layer3_mfma(
    const __hip_bfloat16* __restrict__ z2, const unsigned short* __restrict__ w3t,
    const float* __restrict__ b3,
    const float* __restrict__ aS, const float* __restrict__ cS,
    __hip_bfloat16* __restrict__ z3,
    float* __restrict__ dsum, float* __restrict__ dsq, int C) {
    __shared__ unsigned short tile[64 * 128];   // 16 KB output stage
    __shared__ float sps[2][128];
    __shared__ float spq[2][128];
    __shared__ float aSs[64], cSs[64];
    int tid = threadIdx.x, wid = tid >> 6, lane = tid & 63;
    int wm = wid >> 1, wn = wid & 1;
    int c0 = blockIdx.x * 64;
    int l15 = lane & 15, l4 = lane >> 4;
    const unsigned short* z2u = (const unsigned short*)z2;
    if (tid < 64) { aSs[tid] = aS[tid]; cSs[tid] = cS[tid]; }
    __syncthreads();

    bf16x8 afrag[2][2];
    int rowA0 = c0 + wm * 32 + l15;
    #pragma unroll
    for (int ks = 0; ks < 2; ++ks) {
        int k0 = ks * 32 + l4 * 8;
        #pragma unroll
        for (int mi = 0; mi < 2; ++mi) {
            int r = rowA0 + mi * 16;
            int rc = (r < C) ? r : (C - 1);
            bf16x8 raw = *(const bf16x8*)&z2u[(size_t)rc * 64 + k0];
            bf16x8 af;
            #pragma unroll
            for (int j = 0; j < 8; ++j) {
                float v = bf2f((unsigned short)raw[j]);
                float hx = fmaxf(fmaf(aSs[k0 + j], v, cSs[k0 + j]), 0.f);
                af[j] = (short)f2bfu((r < C) ? hx : 0.f);
            }
            afrag[mi][ks] = af;
        }
    }

    f32x4 acc[2][4];
    #pragma unroll
    for (int mi = 0; mi < 2; ++mi)
        #pragma unroll
        for (int ni = 0; ni < 4; ++ni)
            acc[mi][ni] = (f32x4){0.f, 0.f, 0.f, 0.f};
    #pragma unroll
    for (int ks = 0; ks < 2; ++ks) {
        int k0 = ks * 32 + l4 * 8;
        bf16x8 bfrag[4];
        #pragma unroll
        for (int ni = 0; ni < 4; ++ni) {
            int n = wn * 64 + ni * 16 + l15;
            bfrag[ni] = *(const bf16x8*)&w3t[(size_t)n * 64 + k0];
        }
        #pragma unroll
        for (int mi = 0; mi < 2; ++mi)
            #pragma unroll
            for (int ni = 0; ni < 4; ++ni)
                acc[mi][ni] = __builtin_amdgcn_mfma_f32_16x16x32_bf16(
                    afrag[mi][ks], bfrag[ni], acc[mi][ni], 0, 0, 0);
    }
    #pragma unroll
    for (int ni = 0; ni < 4; ++ni) {
        int col = wn * 64 + ni * 16 + l15;
        float bv = b3[col];
        float s = 0.f, q = 0.f;
        #pragma unroll
        for (int mi = 0; mi < 2; ++mi) {
            #pragma unroll
            for (int r = 0; r < 4; ++r) {
                int lrow = wm * 32 + mi * 16 + l4 * 4 + r;
                float z = acc[mi][ni][r] + bv;
                int sc = (col & 7) + 8 * ((col >> 3) ^ ((lrow >> 2) & 7));
                tile[lrow * 128 + sc] = f2bfu(z);
                if (c0 + lrow < C) { s += z; q += z * z; }
            }
        }
        s += __shfl_xor(s, 16); s += __shfl_xor(s, 32);
        q += __shfl_xor(q, 16); q += __shfl_xor(q, 32);
        if (lane < 16) { sps[wm][col] = s; spq[wm][col] = q; }
    }
    __syncthreads();
    if (tid < 128) {
        float s = sps[0][tid] + sps[1][tid];
        float q = spq[0][tid] + spq[1][tid];
        size_t cb = (size_t)(blockIdx.x & (NDCOPY - 1)) * DSTRIDE;
        unsafeAtomicAdd(&dsum[cb + tid], s);
        unsafeAtomicAdd(&dsq[cb + tid],  q);
    }
    unsigned short* z3u = (unsigned short*)z3;
    #pragma unroll
    for (int k = 0; k < 4; ++k) {
        int ch = k * 256 + tid;          // 1024 chunks of 16B
        int lrow = ch >> 4;              // 16 chunks per 256B row
        int c8 = ch & 15;
        if (c0 + lrow < C)
            *(bf16x8*)&z3u[(size_t)(c0 + lrow) * 128 + c8 * 8] =
                *(bf16x8*)&tile[lrow * 128 + 8 * (c8 ^ ((lrow >> 2) & 7))];
    }
}

// --- layer 4 via MFMA: A-in-regs, N-split acc, swizzled 32KB LDS stage ----
__global__ __launch_bounds__(256, 3) void layer4_mfma(
    const __hip_bfloat16* __restrict__ z3, const unsigned short* __restrict__ w4t,
    const float* __restrict__ b4,
    const float* __restrict__ aS, const float* __restrict__ cS,
    __hip_bfloat16* __restrict__ z4,
    float* __restrict__ dsum, float* __restrict__ dsq, int C) {
    __shared__ unsigned short tile[64 * 256];   // 32 KB output stage
    __shared__ float sps[2][256];
    __shared__ float spq[2][256];
    __shared__ float aSs[128], cSs[128];
    int tid = threadIdx.x, wid = tid >> 6, lane = tid & 63;
    int wm = wid >> 1, wn = wid & 1;
    int c0 = blockIdx.x * 64;
    int l15 = lane & 15, l4 = lane >> 4;
    const unsigned short* z3u = (const unsigned short*)z3;
    if (tid < 128) { aSs[tid] = aS[tid]; cSs[tid] = cS[tid]; }
    __syncthreads();

    bf16x8 afrag[2][4];
    int rowA0 = c0 + wm * 32 + l15;
    #pragma unroll
    for (int ks = 0; ks < 4; ++ks) {
        int k0 = ks * 32 + l4 * 8;
        #pragma unroll
        for (int mi = 0; mi < 2; ++mi) {
            int r = rowA0 + mi * 16;
            int rc = (r < C) ? r : (C - 1);
            bf16x8 raw = *(const bf16x8*)&z3u[(size_t)rc * 128 + k0];
            bf16x8 af;
            #pragma unroll
            for (int j = 0; j < 8; ++j) {
                float v = bf2f((unsigned short)raw[j]);
                float hx = fmaxf(fmaf(aSs[k0 + j], v, cSs[k0 + j]), 0.f);
                af[j] = (short)f2bfu((r < C) ? hx : 0.f);
            }
            afrag[mi][ks] = af;
        }
    }

    #pragma unroll
    for (int nh = 0; nh < 2; ++nh) {
        f32x4 acc[2][4];
        #pragma unroll
        for (int mi = 0; mi < 2; ++mi)
            #pragma unroll
            for (int ni = 0; ni < 4; ++ni)
                acc[mi][ni] = (f32x4){0.f, 0.f, 0.f, 0.f};
        #pragma unroll
        for (int ks = 0; ks < 4; ++ks) {
            int k0 = ks * 32 + l4 * 8;
            bf16x8 bfrag[4];
            #pragma unroll
            for (int ni = 0; ni < 4; ++ni) {
                int n = wn * 128 + nh * 64 + ni * 16 + l15;
                bfrag[ni] = *(const bf16x8*)&w4t[(size_t)n * 128 + k0];
            }
            #pragma unroll
            for (int mi = 0; mi < 2; ++mi)
                #pragma unroll
                for (int ni = 0; ni < 4; ++ni)
                    acc[mi][ni] = __builtin_amdgcn_mfma_f32_16x16x32_bf16(
                        afrag[mi][ks], bfrag[ni], acc[mi][ni], 0, 0, 0);
        }
        #pragma unroll
        for (int ni = 0; ni < 4; ++ni) {
            int col = wn * 128 + nh * 64 + ni * 16 + l15;
            float bv = b4[col];
            float s = 0.f, q = 0.f;
            #pragma unroll
            for (int mi = 0; mi < 2; ++mi) {
                #pragma unroll
                for (int r = 0; r < 4; ++r) {
                    int lrow = wm * 32 + mi * 16 + l4 * 4 + r;
                    float z = acc[mi][ni][r] + bv;
                    int sc = (col & 7) + 8 * ((col >> 3) ^ ((lrow >> 2) & 7));
                    tile[lrow * 256 + sc] = f2bfu(z);
                    if (c0 + lrow < C) { s += z; q += z * z; }
                }
            }
            s += __shfl_xor(s, 16); s += __shfl_xor(s, 32);
            q += __shfl_xor(q, 16); q += __shfl_xor(q, 32);
            if (lane < 16) { sps[wm][col] = s; spq[wm][col] = q; }
        }
    }
    __syncthreads();
    if (tid < 256) {
        float s = sps[0][tid] + sps[1][tid];
        float q = spq[0][tid] + spq[1][tid];
        size_t cb = (size_t)(blockIdx.x & (NDCOPY - 1)) * DSTRIDE;
        unsafeAtomicAdd(&dsum[cb + tid], s);
        unsafeAtomicAdd(&dsq[cb + tid],  q);
    }
    unsigned short* z4u = (unsigned short*)z4;
    #pragma unroll
    for (int k = 0; k < 8; ++k) {
        int ch = k * 256 + tid;         // 2048 chunks of 16B
        int lrow = ch >> 5;             // 32 chunks per 512B row
        int c8 = ch & 31;
        if (c0 + lrow < C)
            *(bf16x8*)&z4u[(size_t)(c0 + lrow) * 256 + c8 * 8] =
                *(bf16x8*)&tile[lrow * 256 + 8 * (c8 ^ ((lrow >> 2) & 7))];
    }
}

// -- segment-sum of relu(bn4(z4)): precomputed aS/cS -----------------------
__global__ __launch_bounds__(256) void pool_kernel(
    const __hip_bfloat16* __restrict__ z4, const int* __restrict__ imgid,
    const float* __restrict__ aS, const float* __restrict__ cS,
    float* __restrict__ pool, int C, int B) {
    __shared__ float spool[64 * 256];
    int tid = threadIdx.x;
    int nb = B * 256;
    for (int t = tid; t < nb; t += 256) spool[t] = 0.f;
    __syncthreads();
    float a = aS[tid], cc = cS[tid];
    int per  = (C + gridDim.x - 1) / gridDim.x;
    int cbeg = blockIdx.x * per;
    int cend = min(cbeg + per, C);
    int c = cbeg;
    for (; c + 16 <= cend; c += 16) {
        float v[16];
        int im[16];
        #pragma unroll
        for (int u = 0; u < 16; ++u) {
            im[u] = imgid[c + u];
            v[u] = loadv(z4, (size_t)(c + u) * 256 + tid);
        }
        #pragma unroll
        for (int u = 0; u < 16; ++u) {
            float hv = fmaxf(fmaf(a, v[u], cc), 0.f);
            spool[im[u] * 256 + tid] += hv;
        }
    }
    for (; c < cend; ++c) {
        int img = imgid[c];
        float v = loadv(z4, (size_t)c * 256 + tid);
        float hv = fmaxf(fmaf(a, v, cc), 0.f);
        spool[img * 256 + tid] += hv;
    }
    __syncthreads();
    float* dst = pool + (size_t)(blockIdx.x & (NPOOL - 1)) * nb;
    int start = ((int)blockIdx.x * 2048) % nb;
    for (int t0 = 0; t0 < nb; t0 += 256) {
        int t = (start + t0 + tid) % nb;
        unsafeAtomicAdd(&dst[t], spool[t]);
    }
}

// ---------- mean over comps (sum NPOOL copies), BN over 64 image rows -----
__global__ void bn5_kernel(const float* __restrict__ pool,
                           const int* __restrict__ pcnt,
                           const float* __restrict__ g5,
                           const float* __restrict__ be5,
                           float* __restrict__ y, int B) {
    int ch = threadIdx.x;
    int nb = B * 256;
    double s = 0.0, s2 = 0.0;
    float vals[64];
    for (int b = 0; b < B; ++b) {
        float v = 0.f;
        #pragma unroll
        for (int k = 0; k < NPOOL; ++k) v += pool[k * nb + b * 256 + ch];
        float c = (float)pcnt[b]; if (c < 1.f) c = 1.f;
        v /= c;
        vals[b] = v;
        s += (double)v; s2 += (double)v * (double)v;
    }
    double m = s / (double)B;
    double var = s2 / (double)B - m * m;
    float rs = rsqrtf((float)var + BN_EPS);
    float a = g5[ch] * rs;
    float cc = be5[ch] - (float)m * a;
    for (int b = 0; b < B; ++b)
        y[b * 256 + ch] = fmaf(a, vals[b], cc);
}

// ------------------------------------------------------- final FC + ReLU
__global__ __launch_bounds__(256) void fc_kernel(
    const float* __restrict__ y, const float* __restrict__ Wfc,
    const float* __restrict__ bfc, float* __restrict__ out, int NC) {
    int b = blockIdx.y;
    int ch = blockIdx.x * 256 + threadIdx.x;
    __shared__ float sy[256];
    sy[threadIdx.x] = y[b * 256 + threadIdx.x];
    __syncthreads();
    if (ch < NC) {
        float acc = bfc[ch];
        for (int k = 0; k < 256; ++k)
            acc = fmaf(sy[k], Wfc[(size_t)k * NC + ch], acc);
        out[(size_t)b * NC + ch] = fmaxf(acc, 0.f);
    }
}

// ---------------------------------------------------------------- launcher
extern "C" void kernel_launch(void* const* d_in, const int* in_sizes, int n_in,
                              void* d_out, int out_size, void* d_ws,
                              size_t ws_size, hipStream_t stream) {
    const float* item_feat = (const float*)d_in[0];
    const int*   ccids     = (const int*)d_in[1];
    const int*   imgid     = (const int*)d_in[2];
    const float* W1  = (const float*)d_in[3];
    const float* b1  = (const float*)d_in[4];
    const float* g1  = (const float*)d_in[5];
    const float* be1 = (const float*)d_in[6];
    const float* W2  = (const float*)d_in[7];
    const float* b2  = (const float*)d_in[8];
    const float* g2  = (const float*)d_in[9];
    const float* be2 = (const float*)d_in[10];
    const float* W3  = (const float*)d_in[11];
    const float* b3  = (const float*)d_in[12];
    const float* g3  = (const float*)d_in[13];
    const float* be3 = (const float*)d_in[14];
    const float* W4  = (const float*)d_in[15];
    const float* b4  = (const float*)d_in[16];
    const float* g4  = (const float*)d_in[17];
    const float* be4 = (const float*)d_in[18];
    const float* g5  = (const float*)d_in[19];
    const float* be5 = (const float*)d_in[20];
    const float* Wfc = (const float*)d_in[21];
    const float* bfc = (const float*)d_in[22];
    float* out = (float*)d_out;

    const int N  = in_sizes[1];
    const int C  = in_sizes[2];
    const int NC = in_sizes[22];
    const int B  = out_size / NC;

    uint8_t* ws = (uint8_t*)d_ws;
    size_t off_ = 0;
    auto alloc = [&](size_t bytes) -> void* {
        void* p = (void*)(ws + off_);
        off_ += (bytes + 255) & ~(size_t)255;
        return p;
    };
    int*    sbsize = (int*)alloc((size_t)NSBMAX * 4);
    float*  fstats = (float*)alloc((size_t)NDCOPY * DSTRIDE * 4);  // 360 KB
    int*    pcnt   = (int*)alloc((size_t)B * 4);
    float*  pool   = (float*)alloc((size_t)NPOOL * B * 256 * 4);
    size_t zeroBytes = off_;
    float*  y      = (float*)alloc((size_t)B * 256 * 4);
    float*  scales = (float*)alloc((size_t)(32 + 64 + 128 + 256) * 2 * 4);
    int*    cnt    = (int*)alloc((size_t)C * 4);
    int*    off    = (int*)alloc((size_t)C * 4);
    int*    sboff  = (int*)alloc((size_t)(NSBMAX + 1) * 4);
    int*    sbcur  = (int*)alloc((size_t)NSBMAX * 4);
    int*    bcur   = (int*)alloc((size_t)8 * 4);
    unsigned short* w4t = (unsigned short*)alloc((size_t)256 * 128 * 2);
    unsigned short* w1t = (unsigned short*)alloc((size_t)32 * 352 * 2);
    unsigned short* w3t = (unsigned short*)alloc((size_t)128 * 64 * 2);
    void* regionA = alloc((size_t)N * 16);
    void* regionB = alloc((size_t)C * 256 * 2);
    (void)ws_size;

    i32x4*           bstage  = (i32x4*)regionB;
    i32x4*           bstage2 = (i32x4*)regionA;
    i32x4*           srec    = (i32x4*)regionB;
    __hip_bfloat16*  z1      = (__hip_bfloat16*)regionA;  // C x 32 bf16
    __hip_bfloat16*  z3      = (__hip_bfloat16*)regionA;  // C x 128 bf16 (after z1)
    __hip_bfloat16*  z2      = (__hip_bfloat16*)regionB;  // C x 64 bf16
    __hip_bfloat16*  z4      = (__hip_bfloat16*)regionB;  // C x 256 bf16

    float *ds1 = fstats +   0, *dq1 = fstats +  32;
    float *ds2 = fstats +  64, *dq2 = fstats + 128;
    float *ds3 = fstats + 192, *dq3 = fstats + 320;
    float *ds4 = fstats + 448, *dq4 = fstats + 704;
    float *aS1 = scales +   0, *cS1 = scales +  32;
    float *aS2 = scales +  64, *cS2 = scales + 128;
    float *aS3 = scales + 192, *cS3 = scales + 320;
    float *aS4 = scales + 448, *cS4 = scales + 704;

    const int cg     = (C + 7) / 8;        // 25000
    const int nsb    = (cg + 127) / 128;   // 196
    const int nsbtot = 8 * nsb;            // 1568 (<= NSBMAX)

    hipMemsetAsync(ws, 0, zeroBytes, stream);
    hist_kernel<<<512, 256, 0, stream>>>((const i32x4*)ccids, sbsize,
                                         imgid, pcnt, N / 4, C, cg, nsb, B);
    prep_kernel<<<205, 256, 0, stream>>>(W4, W1, W3, w4t, w1t, w3t);
    scan_sb<<<1, 256, 0, stream>>>(sbsize, sboff, sbcur, bcur, nsbtot, nsb, N);
    bucketA_kernel<<<(N + ACHUNK - 1) / ACHUNK, 256, 0, stream>>>(
        ccids, item_feat, bcur, bstage, N, cg);
    bucketB2_kernel<<<1960, 256, 0, stream>>>(bstage, sboff, sbcur, bstage2,
                                              N, C, cg, nsb);
    bucketC_kernel<<<8 * 256, 256, 0, stream>>>(bstage2, sboff, srec,
                                                cnt, off, N, C, cg, nsb);

    layer1_mfma<<<(C + 63) / 64, 256, 0, stream>>>(srec, cnt, off,
                                                   w1t, b1, z1, ds1, dq1, C);
    finalize_kernel<32><<<1, 32, 0, stream>>>(ds1, dq1, g1, be1, aS1, cS1, C);

    layer_kernel<__hip_bfloat16, __hip_bfloat16, 32, 64, 4, 8>
        <<<(C + 127) / 128, 256, 0, stream>>>(z1, W2, b2, aS1, cS1,
                                              z2, ds2, dq2, C);
    finalize_kernel<64><<<1, 64, 0, stream>>>(ds2, dq2, g2, be2, aS2, cS2, C);

    layer3_mfma<<<(C + 63) / 64, 256, 0, stream>>>(z2, w3t, b3, aS2, cS2,
                                                   z3, ds3, dq3, C);
    finalize_kernel<128><<<1, 128, 0, stream>>>(ds3, dq3, g3, be3, aS3, cS3, C);

    layer4_mfma<<<(C + 63) / 64, 256, 0, stream>>>(z3, w4t, b4, aS3, cS3,
                                                   z4, ds4, dq4, C);
    finalize_kernel<256><<<1, 256, 0, stream>>>(ds4, dq4, g4, be4, aS4, cS4, C);

    pool_kernel<<<512, 256, 0, stream>>>(z4, imgid, aS4, cS4, pool, C, B);
    bn5_kernel<<<1, 256, 0, stream>>>(pool, pcnt, g5, be5, y, B);

    dim3 fcg((NC + 255) / 256, B);
    fc_kernel<<<fcg, 256, 0, stream>>>(y, Wfc, bfc, out, NC);
}